// Round 15
// baseline (174.764 us; speedup 1.0000x reference)
//
#include <hip/hip_runtime.h>
#include <hip/hip_bf16.h>

// BertSelfAttention B=4,S=1024,HID=1024,H=16,D=64,MAXP=1024 — Round 22.
// R21 post-mortem: cooperative fusion never launched (absmax 0.1396 ==
// max|ref| => all-zero output; hipLaunchCooperativeKernel rejected the
// grid, return code unchecked). Coop fusion is DEAD on this harness.
// Salvage: the prep restructure from R21 needs no coop. prep was 3648
// tiny blocks (14+ rounds, 2 barriers each) — latency-bound launch storm,
// plausibly 30-40us of the invisible 113.
// R22 = R20 (174.4us verified) + prep 912 blocks x 4 units: one barrier
// pair per block, 4x loads in flight, consecutive units share hidden rows
// (same mt, 4 kg) for L2 reuse. qkv (3-buf counted-vmcnt) and attn (R17)
// verbatim. Falsification: dTotal < 4us => prep already small; remaining
// budget is qkv + fixed overhead.
// ws: Xs[0,8M) Wt[8M,14M) Db[14M,14.25M) Qf[15M) Kf[23M) Vt[31M)

#define EPSV 1e-8f

typedef short bfrag __attribute__((ext_vector_type(8)));   // 8 bf16
typedef float cfrag __attribute__((ext_vector_type(16)));  // C/D 32x32
typedef int v2i __attribute__((ext_vector_type(2)));
typedef float v2f __attribute__((ext_vector_type(2)));

__device__ __forceinline__ short f2bf(float f) {
    __hip_bfloat16 h = __float2bfloat16(f);
    return *reinterpret_cast<short*>(&h);
}
__device__ __forceinline__ unsigned int pk2(short a, short b) {
    return (unsigned int)(unsigned short)a | ((unsigned int)(unsigned short)b << 16);
}
// async global->LDS DMA, 16B/lane: LDS dst = wave-uniform base + lane*16,
// global src = per-lane address (must include lane*16).
__device__ __forceinline__ void g2lds(const short* g, short* l) {
    __builtin_amdgcn_global_load_lds(
        (const __attribute__((address_space(1))) void*)g,
        (__attribute__((address_space(3))) void*)l, 16, 0, 0);
}

// ---------------------------------------------------------------------------
// prep: fused cvt/swizzle. grid.x = 912, 256 thr, 4 virtual units/block.
// Unit vb: [0,2048) X->Xs frag-major; [2048,3584) W->Wt frag-major
// (transpose); [3584,3648) dist->Db bf16. One barrier pair per block.
__global__ __launch_bounds__(256) void prep(
    const float* __restrict__ hidden, const float* __restrict__ Wq,
    const float* __restrict__ Wk, const float* __restrict__ Wv,
    const float* __restrict__ dist,
    short* __restrict__ Xs, short* __restrict__ Wt, short* __restrict__ Db)
{
    __shared__ short Tl[4][2304];
    const int bid = blockIdx.x, tid = threadIdx.x;

    // half 1: all 4 units' global loads + LDS writes (loads overlap)
#pragma unroll
    for (int u = 0; u < 4; u++) {
        const int vb = bid * 4 + u;
        short* Tu = Tl[u];
        if (vb < 2048) {                   // X: 128 m-tiles x 16 k-groups
            const int mt = vb >> 4, kg = vb & 15;
            const int m_l = tid >> 3, k8 = (tid & 7) * 8;
            const float* src = hidden + (size_t)(mt * 32 + m_l) * 1024 + kg * 64 + k8;
            float4 v0 = *(const float4*)src, v1 = *(const float4*)(src + 4);
            short o[8];
            o[0] = f2bf(v0.x); o[1] = f2bf(v0.y); o[2] = f2bf(v0.z); o[3] = f2bf(v0.w);
            o[4] = f2bf(v1.x); o[5] = f2bf(v1.y); o[6] = f2bf(v1.z); o[7] = f2bf(v1.w);
            *(bfrag*)&Tu[m_l * 72 + k8] = *(bfrag*)o;
        } else if (vb < 3584) {            // W: 3 z x 32 n-tiles x 16 k-grp
            const int t = vb - 2048, z = t >> 9, nt = (t >> 4) & 31, kg = t & 15;
            const float* W = (z == 0) ? Wq : ((z == 1) ? Wk : Wv);
            const int k_l = tid >> 2, n8 = (tid & 3) * 8;
            const float* src = W + (size_t)(kg * 64 + k_l) * 1024 + nt * 32 + n8;
            float4 v0 = *(const float4*)src, v1 = *(const float4*)(src + 4);
            float vv[8] = {v0.x, v0.y, v0.z, v0.w, v1.x, v1.y, v1.z, v1.w};
#pragma unroll
            for (int i = 0; i < 8; i++)
                Tu[(n8 + i) * 72 + k_l] = f2bf(vv[i]);   // transpose into LDS
        } else if (vb < 3648) {            // dist: direct, no LDS
            const int idx = (vb - 3584) * 256 + tid;
            if (idx < 16376) {
                const float* src = dist + (size_t)idx * 8;
                float4 v0 = *(const float4*)src, v1 = *(const float4*)(src + 4);
                short o[8];
                o[0] = f2bf(v0.x); o[1] = f2bf(v0.y); o[2] = f2bf(v0.z); o[3] = f2bf(v0.w);
                o[4] = f2bf(v1.x); o[5] = f2bf(v1.y); o[6] = f2bf(v1.z); o[7] = f2bf(v1.w);
                *(bfrag*)(Db + (size_t)idx * 8) = *(bfrag*)o;
            }
        }
    }
    __syncthreads();
    // half 2: LDS reads + frag-major global stores
    {
        const int l31 = tid & 31, q2 = (tid >> 5) & 1, kc = tid >> 6;
#pragma unroll
        for (int u = 0; u < 4; u++) {
            const int vb = bid * 4 + u;
            const short* Tu = Tl[u];
            if (vb < 2048) {
                const int mt = vb >> 4, kg = vb & 15;
                bfrag r = *(const bfrag*)&Tu[l31 * 72 + kc * 16 + q2 * 8];
                *(bfrag*)(Xs + ((size_t)(mt * 64 + kg * 4 + kc) * 64
                          + q2 * 32 + l31) * 8) = r;
            } else if (vb < 3584) {
                const int t = vb - 2048, z = t >> 9, nt = (t >> 4) & 31, kg = t & 15;
                bfrag r = *(const bfrag*)&Tu[l31 * 72 + kc * 16 + q2 * 8];
                *(bfrag*)(Wt + (size_t)z * 1048576
                          + ((size_t)(nt * 64 + kg * 4 + kc) * 64
                             + q2 * 32 + l31) * 8) = r;
            }
        }
    }
}

// ---------------------------------------------------------------------------
// QKV GEMM — R20 verbatim: 3-buffer counted-vmcnt pipeline. 128x128 block,
// 4 waves. Phase p: vmcnt(4) -> s_barrier -> STAGE(p+2) -> ds_read + MFMA.
// Never vmcnt(0) in loop. Chunk (tile, kc) at tile*32768 + kc*512 shorts.
__global__ __launch_bounds__(256) void qkv_mfma(
    const short* __restrict__ Xs, const short* __restrict__ Wt,
    const float* __restrict__ bq, const float* __restrict__ bk,
    const float* __restrict__ bv,
    short* __restrict__ Qf, short* __restrict__ Kf, short* __restrict__ Vt)
{
    __shared__ alignas(16) short Ab[3][2][4][512];  // [buf][ksub][chunk][1KB]
    __shared__ alignas(16) short Bb[3][2][4][512];

    const int z = blockIdx.z;
    const short* W = Wt + (size_t)z * 1048576;
    const float* bias = (z == 0) ? bq : ((z == 1) ? bk : bv);
    // fold 1/sqrt(D) AND log2(e) into Q: 0.125 * 1.4426950408889634
    const float scale = (z == 0) ? 0.18033688011112042f : 1.0f;

    const int tid = threadIdx.x, lane = tid & 63, wid = tid >> 6;
    const int q2 = lane >> 5, l31 = lane & 31;
    const int wr = wid >> 1, wc = wid & 1;
    const int m0 = blockIdx.x * 128, n0 = blockIdx.y * 128;

    // tile-0 global bases (shorts); tile t at +t*32768, chunk kc at +kc*512
    const short* Ag = Xs + (size_t)(m0 >> 5) * 32768;
    const short* Bg = W  + (size_t)(n0 >> 5) * 32768;

    auto STAGE = [&](int p, int bi) {
        const int k0 = p * 2;
#pragma unroll
        for (int j = 0; j < 2; j++) {
            g2lds(Ag + (size_t)wid * 32768 + (k0 + j) * 512 + lane * 8,
                  &Ab[bi][j][wid][0]);
            g2lds(Bg + (size_t)wid * 32768 + (k0 + j) * 512 + lane * 8,
                  &Bb[bi][j][wid][0]);
        }
    };

    cfrag acc[2][2];
#pragma unroll
    for (int i = 0; i < 2; i++)
#pragma unroll
        for (int j = 0; j < 2; j++)
#pragma unroll
            for (int e = 0; e < 16; e++) acc[i][j][e] = 0.f;

    STAGE(0, 0);
    STAGE(1, 1);

    for (int p = 0; p < 32; p++) {
        if (p < 31) asm volatile("s_waitcnt vmcnt(4)" ::: "memory");
        else        asm volatile("s_waitcnt vmcnt(0)" ::: "memory");
        __builtin_amdgcn_s_barrier();
        if (p + 2 < 32) STAGE(p + 2, (p + 2) % 3);

        const int bi = p % 3;
#pragma unroll
        for (int j = 0; j < 2; j++) {
            bfrag a0 = *(const bfrag*)&Ab[bi][j][2 * wr + 0][lane * 8];
            bfrag a1 = *(const bfrag*)&Ab[bi][j][2 * wr + 1][lane * 8];
            bfrag b0 = *(const bfrag*)&Bb[bi][j][2 * wc + 0][lane * 8];
            bfrag b1 = *(const bfrag*)&Bb[bi][j][2 * wc + 1][lane * 8];
            acc[0][0] = __builtin_amdgcn_mfma_f32_32x32x16_bf16(a0, b0, acc[0][0], 0, 0, 0);
            acc[0][1] = __builtin_amdgcn_mfma_f32_32x32x16_bf16(a0, b1, acc[0][1], 0, 0, 0);
            acc[1][0] = __builtin_amdgcn_mfma_f32_32x32x16_bf16(a1, b0, acc[1][0], 0, 0, 0);
            acc[1][1] = __builtin_amdgcn_mfma_f32_32x32x16_bf16(a1, b1, acc[1][1], 0, 0, 0);
        }
    }

    // epilogue: +bias, (Q: x scale), cvt bf16, scatter frag-major per bh
#pragma unroll
    for (int nt = 0; nt < 2; nt++) {
        const int c = n0 + wc * 64 + nt * 32 + l31;    // channel
        const float bval = bias[c];
        const int h = c >> 6;
        const int d = nt * 32 + l31;                   // c & 63
#pragma unroll
        for (int mt = 0; mt < 2; mt++) {
            const int tok0 = m0 + wr * 64 + mt * 32;
            const int bb = tok0 >> 10, s_base = tok0 & 1023;
            const size_t bhbase = (size_t)(bb * 16 + h) * 65536;
            if (z < 2) {
                short* outp = (z == 0) ? Qf : Kf;
                const size_t fbase = bhbase
                    + ((size_t)((s_base >> 5) * 4 + (d >> 4)) * 64
                       + ((d >> 3) & 1) * 32) * 8 + (d & 7);
#pragma unroll
                for (int reg = 0; reg < 16; reg++) {
                    const int row = (reg & 3) + 8 * (reg >> 2) + 4 * q2;
                    outp[fbase + (size_t)row * 8] = f2bf((acc[mt][nt][reg] + bval) * scale);
                }
            } else {
                // V^T frag-major: elem (d, s): ((d>>5)*64 + (s>>4))*64*8 ...
#pragma unroll
                for (int g = 0; g < 4; g++) {
                    const float e0 = acc[mt][nt][4 * g + 0] + bval;
                    const float e1 = acc[mt][nt][4 * g + 1] + bval;
                    const float e2 = acc[mt][nt][4 * g + 2] + bval;
                    const float e3 = acc[mt][nt][4 * g + 3] + bval;
                    uint2 w2;
                    w2.x = pk2(f2bf(e0), f2bf(e1));
                    w2.y = pk2(f2bf(e2), f2bf(e3));
                    const size_t flat = bhbase
                        + ((size_t)(nt * 64 + (s_base >> 4) + (g >> 1)) * 64
                           + (g & 1) * 32 + l31) * 8 + 4 * q2;
                    *(uint2*)(Vt + flat) = w2;
                }
            }
        }
    }
}

// ---------------------------------------------------------------------------
// Fused attention — R17 verbatim (59.3-61.5us verified). grid (64 bh, 8
// l-tiles), 256 thr (4 waves). Toeplitz ring by r, production one iter
// ahead, T as MFMA C-operand, K/V staged via global_load_lds dbuf.
__global__ __launch_bounds__(256, 2) void attn_mfma(
    const short* __restrict__ Qf, const short* __restrict__ Kf,
    const short* __restrict__ Vt, const short* __restrict__ Db,
    const float* __restrict__ amask, const int* __restrict__ skim,
    float* __restrict__ out)
{
    __shared__ alignas(16) short Tb[128 * 132];   // per-(wave,lane) r-ring
    __shared__ alignas(16) short Kbuf[2][4096];   // 8KB per buf: K chunks
    __shared__ alignas(16) short Vbuf[2][4096];   // 8KB per buf: V chunks
    __shared__ float Lg[1024];                    // g[r] = exp(amask)*skim

    const int tid = threadIdx.x, lane = tid & 63, w = tid >> 6;
    const int q2 = lane >> 5, l31 = lane & 31;
    const int bh = blockIdx.x, b = bh >> 4, hh = bh & 15;
    const int l0 = blockIdx.y * 128;

    const short* Qg = Qf + (size_t)bh * 65536;
    const short* Kg = Kf + (size_t)bh * 65536;
    const short* Vg = Vt + (size_t)bh * 65536;

    auto STAGE = [&](int rk, int bi) {
        const int kbase = (rk >> 5) * 4, vbase = rk >> 4;
#pragma unroll
        for (int j = 0; j < 4; j++) {
            const int c = 4 * w + j;
            if (c < 8) {
                g2lds(Kg + (size_t)(kbase + c) * 512 + lane * 8,
                      &Kbuf[bi][c * 512]);
            } else if (c < 12) {
                g2lds(Vg + (size_t)(vbase + (c - 8)) * 512 + lane * 8,
                      &Vbuf[bi][(c - 8) * 512]);
            } else {
                g2lds(Vg + (size_t)(64 + vbase + (c - 12)) * 512 + lane * 8,
                      &Vbuf[bi][(c - 12 + 4) * 512]);
            }
        }
    };

    {
        const int r4 = tid * 4;
        float4 am = *(const float4*)(amask + b * 1024 + r4);
        int4 sk = *(const int4*)(skim + b * 1024 + r4);
        Lg[r4 + 0] = __expf(am.x) * (float)sk.x;
        Lg[r4 + 1] = __expf(am.y) * (float)sk.y;
        Lg[r4 + 2] = __expf(am.z) * (float)sk.z;
        Lg[r4 + 3] = __expf(am.w) * (float)sk.w;
    }
    __syncthreads();

    // Q B-frags (pre-scaled by log2e/8)
    bfrag qa[4];
#pragma unroll
    for (int c = 0; c < 4; c++)
        qa[c] = *(const bfrag*)(Qg + ((size_t)(((l0 >> 5) + w) * 4 + c) * 64 + lane) * 8);

    cfrag oacc[2];
#pragma unroll
    for (int mt = 0; mt < 2; mt++)
#pragma unroll
        for (int e = 0; e < 16; e++) oacc[mt][e] = 0.f;
    v2f es01 = {0.f, 0.f}, es23 = {0.f, 0.f};

    const int Lband = l0 + 32 * w;          // wave's first l-column
    const int lg = Lband + l31;             // this lane's l-column
    const int rowb = (32 * w + l31) * 132;  // private ring row (shorts)

    for (int r0 = -128; r0 < 1024; r0 += 64) {
        const bool produce = r0 < 960;
        const int cur = (r0 >> 6) & 1;      // consume buffer (valid r0>=0)

        // ---- stage next iteration's K/V (async DMA, full-iter cover) ----
        if (r0 + 64 >= 0 && r0 + 64 < 1024)
            STAGE(r0 + 64, ((r0 + 64) >> 6) & 1);

        // ---- issue production's Db loads early (independent) ----
        bfrag pb[2][4];
        if (produce) {
#pragma unroll
            for (int mt = 0; mt < 2; mt++) {
                const int D0 = Lband - r0 - 128 + 32 * mt;   // dist block base
                const int er = min(max(D0 + l31 + 1023, 0), 2046);
#pragma unroll
                for (int kc = 0; kc < 4; kc++)
                    pb[mt][kc] = *(const bfrag*)(Db + (size_t)er * 64 + kc * 16 + q2 * 8);
            }
        }

        if (r0 >= 0) {
            // ---- K, V frags from staged LDS; ring reads; all hoisted ----
            bfrag kb[2][4], vbl[4][2];
            v2i trr[2][4];
#pragma unroll
            for (int mt = 0; mt < 2; mt++)
#pragma unroll
                for (int kc = 0; kc < 4; kc++)
                    kb[mt][kc] = *(const bfrag*)&Kbuf[cur][(mt * 4 + kc) * 512 + lane * 8];
#pragma unroll
            for (int kc = 0; kc < 4; kc++)
#pragma unroll
                for (int mtd = 0; mtd < 2; mtd++)
                    vbl[kc][mtd] = *(const bfrag*)&Vbuf[cur][(mtd * 4 + kc) * 512 + lane * 8];
#pragma unroll
            for (int mt = 0; mt < 2; mt++)
#pragma unroll
                for (int g = 0; g < 4; g++)
                    trr[mt][g] = *(const v2i*)&Tb[rowb
                        + ((r0 + 32 * mt + 8 * g + 4 * q2) & 127)];

            // ---- per 32-r block: scores (C=T), softmax, relayout, PV ----
#pragma unroll
            for (int mt = 0; mt < 2; mt++) {
                cfrag sfr;
#pragma unroll
                for (int g = 0; g < 4; g++) {
                    const v2i t2 = trr[mt][g];
                    sfr[4 * g + 0] = __builtin_bit_cast(float, (unsigned)t2[0] << 16);
                    sfr[4 * g + 1] = __builtin_bit_cast(float, (unsigned)t2[0] & 0xffff0000u);
                    sfr[4 * g + 2] = __builtin_bit_cast(float, (unsigned)t2[1] << 16);
                    sfr[4 * g + 3] = __builtin_bit_cast(float, (unsigned)t2[1] & 0xffff0000u);
                }
                __builtin_amdgcn_s_setprio(1);
#pragma unroll
                for (int kc = 0; kc < 4; kc++)
                    sfr = __builtin_amdgcn_mfma_f32_32x32x16_bf16(
                        kb[mt][kc], qa[kc], sfr, 0, 0, 0);
                __builtin_amdgcn_s_setprio(0);

                unsigned int P[4][2];
#pragma unroll
                for (int g = 0; g < 4; g++) {
                    const int rb = r0 + 32 * mt + 8 * g + 4 * q2;
                    float4 g4 = *(const float4*)&Lg[rb];
                    float ev0 = __builtin_amdgcn_exp2f(sfr[4 * g + 0]) * g4.x;
                    float ev1 = __builtin_amdgcn_exp2f(sfr[4 * g + 1]) * g4.y;
                    float ev2 = __builtin_amdgcn_exp2f(sfr[4 * g + 2]) * g4.z;
                    float ev3 = __builtin_amdgcn_exp2f(sfr[4 * g + 3]) * g4.w;
                    es01 += (v2f){ev0, ev1};
                    es23 += (v2f){ev2, ev3};
                    P[g][0] = pk2(f2bf(ev0), f2bf(ev1));
                    P[g][1] = pk2(f2bf(ev2), f2bf(ev3));
                }
                // in-register relayout: score C-frag -> PV B-frag
#pragma unroll
                for (int c = 0; c < 2; c++) {
                    v2i s0 = __builtin_amdgcn_permlane32_swap(
                        (int)P[2 * c][0], (int)P[2 * c + 1][0], false, false);
                    v2i s1 = __builtin_amdgcn_permlane32_swap(
                        (int)P[2 * c][1], (int)P[2 * c + 1][1], false, false);
                    union { bfrag f; int d[4]; } u;
                    u.d[0] = s0[0]; u.d[1] = s1[0]; u.d[2] = s0[1]; u.d[3] = s1[1];
                    const int kc = 2 * mt + c;
                    __builtin_amdgcn_s_setprio(1);
#pragma unroll
                    for (int mtd = 0; mtd < 2; mtd++)
                        oacc[mtd] = __builtin_amdgcn_mfma_f32_32x32x16_bf16(
                            vbl[kc][mtd], u.f, oacc[mtd], 0, 0, 0);
                    __builtin_amdgcn_s_setprio(0);
                }
            }
        }

        // ---- production: T window for [r0+64, r0+127] (after gathers) ----
        if (produce) {
#pragma unroll
            for (int mt = 0; mt < 2; mt++) {
                cfrag t;
#pragma unroll
                for (int e = 0; e < 16; e++) t[e] = 0.f;
                __builtin_amdgcn_s_setprio(1);
#pragma unroll
                for (int kc = 0; kc < 4; kc++)
                    t = __builtin_amdgcn_mfma_f32_32x32x16_bf16(
                        pb[mt][kc], qa[kc], t, 0, 0, 0);
                __builtin_amdgcn_s_setprio(0);
#pragma unroll
                for (int e = 0; e < 16; e++) {
                    const int rr = (e & 3) + 8 * (e >> 2) + 4 * q2;
                    Tb[rowb + ((l31 + r0 - 32 * mt - rr) & 127)] = f2bf(t[e]);
                }
            }
        }

        // barrier: (a) completes next iter's staged DMA (implicit vmcnt
        // drain), (b) orders buf reuse across waves. Tb is wave-private.
        __syncthreads();
    }

    // ---- finalize ----
    float esum = (es01[0] + es01[1]) + (es23[0] + es23[1]);
    const float den = EPSV + esum + __shfl_xor(esum, 32);
    const float inv = 1.0f / den;
    float* ob = out + ((size_t)(b * 1024 + lg) * 1024) + hh * 64;
#pragma unroll
    for (int mtd = 0; mtd < 2; mtd++) {
#pragma unroll
        for (int g = 0; g < 4; g++) {
            float4 o;
            o.x = oacc[mtd][4 * g + 0] * inv;
            o.y = oacc[mtd][4 * g + 1] * inv;
            o.z = oacc[mtd][4 * g + 2] * inv;
            o.w = oacc[mtd][4 * g + 3] * inv;
            *(float4*)(ob + 32 * mtd + 8 * g + 4 * q2) = o;
        }
    }
}

// ---------------------------------------------------------------------------
extern "C" void kernel_launch(void* const* d_in, const int* in_sizes, int n_in,
                              void* d_out, int out_size, void* d_ws, size_t ws_size,
                              hipStream_t stream) {
    const float* hidden = (const float*)d_in[0];
    const float* amask  = (const float*)d_in[1];
    const int*   skim   = (const int*)d_in[2];
    const float* Wq     = (const float*)d_in[3];
    const float* bq     = (const float*)d_in[4];
    const float* Wk     = (const float*)d_in[5];
    const float* bk     = (const float*)d_in[6];
    const float* Wv     = (const float*)d_in[7];
    const float* bv     = (const float*)d_in[8];
    const float* dist   = (const float*)d_in[9];
    float* out = (float*)d_out;

    char* w = (char*)d_ws;
    short* Xs  = (short*)(w);                        // 8 MB frag-major X
    short* Wt  = (short*)(w + ((size_t)8 << 20));    // 6 MB frag-major W^T
    short* Db  = (short*)(w + ((size_t)14 << 20));   // 0.25 MB dist bf16
    short* Qf  = (short*)(w + ((size_t)15 << 20));   // 8 MB frag-major Q
    short* Kf  = (short*)(w + ((size_t)23 << 20));   // 8 MB frag-major K
    short* Vt  = (short*)(w + ((size_t)31 << 20));   // 8 MB frag-major V^T

    prep<<<912, 256, 0, stream>>>(hidden, Wq, Wk, Wv, dist, Xs, Wt, Db);
    qkv_mfma<<<dim3(32, 8, 3), 256, 0, stream>>>(Xs, Wt, bq, bk, bv, Qf, Kf, Vt);
    attn_mfma<<<dim3(64, 8), 256, 0, stream>>>(Qf, Kf, Vt, Db, amask, skim, out);
}